// Round 6
// baseline (142.329 us; speedup 1.0000x reference)
//
#include <hip/hip_runtime.h>

typedef __bf16 bf16x8 __attribute__((ext_vector_type(8)));
typedef __bf16 bf16x4 __attribute__((ext_vector_type(4)));
typedef float  f32x4  __attribute__((ext_vector_type(4)));

#define NPIX  3136      // 56*56 = 49*64 = 98*32 (no tails)
#define WIMG  56
#define CCH   128
#define NH    4
#define HD    32
#define NSPLIT 8        // key-splits per (head, 32q) tile
// 32^-0.5 * log2(e): q pre-scaled so softmax uses exp2 directly
#define QSCALE 0.2550565470841439f

#if __has_builtin(__builtin_amdgcn_exp2f)
#define FEXP2(x) __builtin_amdgcn_exp2f(x)
#else
#define FEXP2(x) __expf((x) * 0.6931471805599453f)
#endif

// MFMA 16x16x32 fragment maps (HW-verified R1-R5):
//   A[m=lane&15][k=(lane>>4)*8+j]   B[k=(lane>>4)*8+j][n=lane&15]
//   D: col(n)=lane&15, row(m)=(lane>>4)*4+reg
// Key permutation inside each 64-key block: storage slot s holds key
// 16*(s&3)+(s>>2), so QK chunk-c output packs to slot 4*col+c (one b64 LDS
// write per lane); vP is pre-permuted to match (free: permutes a sum index).

// ---------------------------------------------------------------------------
// K1: qkv = qkv_w @ x + qkv_b, bf16 MFMA (M=384, K=128, N=6272).
// grid (49, 3, 2) = 294 blocks, block 256. Slab = 128 outputs (q | k | v),
// so x is staged only 3x (was 6x). Wave = 32 outs x 64 px = 32 MFMAs.
// ---------------------------------------------------------------------------
__global__ __launch_bounds__(256) void k_qkv(
    const float* __restrict__ x, const float* __restrict__ qkv_w,
    const float* __restrict__ qkv_b,
    __bf16* __restrict__ qT, __bf16* __restrict__ kT,
    __bf16* __restrict__ vT, __bf16* __restrict__ vP)
{
    __shared__ __bf16 xl[64][136];                 // [px][c], row stride 272B
    const int tid = threadIdx.x;
    const int w = tid >> 6, lane = tid & 63;
    const int col = lane & 15, g = lane >> 4;
    const int px0 = blockIdx.x * 64;
    const int slab = blockIdx.y;                   // 0 q, 1 k, 2 v
    const int b = blockIdx.z;
    const int obase = slab * 128 + w * 32;

    {   // stage x tile (coalesced dword loads, packed b64 LDS writes)
        const int px = tid & 63, cq = tid >> 6;
        const float* xp = x + (size_t)b * CCH * NPIX + px0 + px;
        #pragma unroll
        for (int i = 0; i < 8; ++i) {
            const int c0 = cq * 4 + i * 16;
            const float v0 = xp[(size_t)(c0 + 0) * NPIX];
            const float v1 = xp[(size_t)(c0 + 1) * NPIX];
            const float v2 = xp[(size_t)(c0 + 2) * NPIX];
            const float v3 = xp[(size_t)(c0 + 3) * NPIX];
            bf16x4 bv = {(__bf16)v0, (__bf16)v1, (__bf16)v2, (__bf16)v3};
            *(bf16x4*)&xl[px][c0] = bv;
        }
    }
    __syncthreads();

    f32x4 acc[2][4];                               // [out tile][px tile]
    #pragma unroll
    for (int ot = 0; ot < 2; ++ot)
        #pragma unroll
        for (int a = 0; a < 4; ++a) acc[ot][a] = (f32x4){0.f, 0.f, 0.f, 0.f};

    #pragma unroll
    for (int ks = 0; ks < 4; ++ks) {
        const int c0 = ks * 32 + g * 8;
        #pragma unroll
        for (int ot = 0; ot < 2; ++ot) {
            const float* wrow = qkv_w + (size_t)(obase + ot * 16 + col) * CCH + c0;
            const float4 wA = *(const float4*)(wrow);
            const float4 wB = *(const float4*)(wrow + 4);
            bf16x8 af = {(__bf16)wA.x, (__bf16)wA.y, (__bf16)wA.z, (__bf16)wA.w,
                         (__bf16)wB.x, (__bf16)wB.y, (__bf16)wB.z, (__bf16)wB.w};
            #pragma unroll
            for (int a = 0; a < 4; ++a) {
                const bf16x8 bf_ = *(const bf16x8*)&xl[16 * a + col][c0];  // one b128
                acc[ot][a] = __builtin_amdgcn_mfma_f32_16x16x32_bf16(af, bf_, acc[ot][a], 0, 0, 0);
            }
        }
    }

    #pragma unroll
    for (int ot = 0; ot < 2; ++ot) {
        const int orow = obase + ot * 16 + g * 4;      // global output row
        const f32x4 bias4 = *(const f32x4*)(qkv_b + orow);
        if (slab == 0) {                               // ---- q (scaled) ----
            const int o = orow, h = o >> 5, d0 = o & 31;
            __bf16* dst = qT + ((size_t)(b * NH + h) * NPIX) * HD + d0;
            #pragma unroll
            for (int a = 0; a < 4; ++a) {
                const int px = px0 + 16 * a + col;
                bf16x4 v;
                #pragma unroll
                for (int r = 0; r < 4; ++r) v[r] = (__bf16)((acc[ot][a][r] + bias4[r]) * QSCALE);
                *(bf16x4*)(dst + (size_t)px * HD) = v;
            }
        } else if (slab == 1) {                        // ---- k ----
            const int o = orow - 128, h = o >> 5, d0 = o & 31;
            __bf16* dst = kT + ((size_t)(b * NH + h) * NPIX) * HD + d0;
            #pragma unroll
            for (int a = 0; a < 4; ++a) {
                const int px = px0 + 16 * a + col;
                bf16x4 v;
                #pragma unroll
                for (int r = 0; r < 4; ++r) v[r] = (__bf16)(acc[ot][a][r] + bias4[r]);
                *(bf16x4*)(dst + (size_t)px * HD) = v;
            }
        } else {                                       // ---- v: vT + permuted vP ----
            const int c = orow - 256;
            #pragma unroll
            for (int a = 0; a < 4; ++a) {
                const int px = px0 + 16 * a + col;
                bf16x4 v;
                #pragma unroll
                for (int r = 0; r < 4; ++r) v[r] = (__bf16)(acc[ot][a][r] + bias4[r]);
                *(bf16x4*)(vT + ((size_t)(b * NPIX + px)) * CCH + c) = v;
                const int sp = px0 + 4 * col + a;      // permuted slot of key px
                #pragma unroll
                for (int r = 0; r < 4; ++r)
                    vP[((size_t)(b * CCH + c + r)) * NPIX + sp] = v[r];
            }
        }
    }
}

// ---------------------------------------------------------------------------
// K2: attention partials. 2 independent waves per WG (128 thr, no barriers,
// wave-private LDS) -- doubles resident waves under the per-CU WG cap.
// grid (49, 8, 8): wave handles (qtile 2*bx+w, head, split) = 32q x 6-7
// key-chunks. NO VGPR cap, NO ping-pong: TLP (~24 waves/CU) hides L2 latency.
// Row-sums via MFMA against all-ones B. Outputs UNNORMALIZED partials:
// pO bf16 [t][s][q 32][d 32] (coalesced for the reducer), pl f32 [t][s][q].
// ---------------------------------------------------------------------------
__global__ __launch_bounds__(128) void k_attn(
    const __bf16* __restrict__ qT, const __bf16* __restrict__ kT,
    const __bf16* __restrict__ vP,
    __bf16* __restrict__ pO, float* __restrict__ pl)
{
    __shared__ __bf16 P[2][32][72];        // per-wave P tile
    const int tid = threadIdx.x;
    const int w = tid >> 6, lane = tid & 63;
    const int col = lane & 15, g = lane >> 4;
    const int qt = blockIdx.x * 2 + w;
    const int bh = blockIdx.y, sp = blockIdx.z;
    const int b = bh >> 2, h = bh & 3;
    const int qbase = qt * 32;
    const size_t headoff = (size_t)bh * NPIX * HD;
    const int c0h = h * HD;

    const bf16x8 aqA = *(const bf16x8*)(qT + headoff + (size_t)(qbase + col) * HD + g * 8);
    const bf16x8 aqB = *(const bf16x8*)(qT + headoff + (size_t)(qbase + 16 + col) * HD + g * 8);

    const __bf16 one = (__bf16)1.0f;
    const bf16x8 ones = {one, one, one, one, one, one, one, one};

    f32x4 O[2][2], Lacc[2];
    #pragma unroll
    for (int i = 0; i < 2; ++i) {
        Lacc[i] = (f32x4){0.f, 0.f, 0.f, 0.f};
        #pragma unroll
        for (int j = 0; j < 2; ++j) O[i][j] = (f32x4){0.f, 0.f, 0.f, 0.f};
    }

    const __bf16* kTh   = kT + headoff;
    const __bf16* vrow0 = vP + (size_t)(b * CCH + c0h + col)      * NPIX;
    const __bf16* vrow1 = vP + (size_t)(b * CCH + c0h + 16 + col) * NPIX;

    const int cs = (49 * sp) >> 3, ce = (49 * (sp + 1)) >> 3;   // 6 or 7 chunks

    for (int cc = cs; cc < ce; ++cc) {
        const int k0 = cc * 64;
        bf16x8 bk0 = *(const bf16x8*)(kTh + (size_t)(k0      + col) * HD + g * 8);
        bf16x8 bk1 = *(const bf16x8*)(kTh + (size_t)(k0 + 16 + col) * HD + g * 8);
        bf16x8 bk2 = *(const bf16x8*)(kTh + (size_t)(k0 + 32 + col) * HD + g * 8);
        bf16x8 bk3 = *(const bf16x8*)(kTh + (size_t)(k0 + 48 + col) * HD + g * 8);
        const bf16x8 bv0 = *(const bf16x8*)(vrow0 + k0      + g * 8);
        const bf16x8 bv1 = *(const bf16x8*)(vrow0 + k0 + 32 + g * 8);
        const bf16x8 bv2 = *(const bf16x8*)(vrow1 + k0      + g * 8);
        const bf16x8 bv3 = *(const bf16x8*)(vrow1 + k0 + 32 + g * 8);
        const f32x4 z = {0.f, 0.f, 0.f, 0.f};
        #pragma unroll
        for (int qh = 0; qh < 2; ++qh) {
            const bf16x8 aq = qh ? aqB : aqA;
            f32x4 s0 = __builtin_amdgcn_mfma_f32_16x16x32_bf16(aq, bk0, z, 0, 0, 0);
            f32x4 s1 = __builtin_amdgcn_mfma_f32_16x16x32_bf16(aq, bk1, z, 0, 0, 0);
            f32x4 s2 = __builtin_amdgcn_mfma_f32_16x16x32_bf16(aq, bk2, z, 0, 0, 0);
            f32x4 s3 = __builtin_amdgcn_mfma_f32_16x16x32_bf16(aq, bk3, z, 0, 0, 0);
            #pragma unroll
            for (int r = 0; r < 4; ++r) {
                bf16x4 pv = {(__bf16)FEXP2(s0[r]), (__bf16)FEXP2(s1[r]),
                             (__bf16)FEXP2(s2[r]), (__bf16)FEXP2(s3[r])};
                *(bf16x4*)&P[w][qh * 16 + g * 4 + r][4 * col] = pv;   // one b64
            }
        }
        #pragma unroll
        for (int qh = 0; qh < 2; ++qh) {
            const bf16x8 ap0 = *(const bf16x8*)&P[w][qh * 16 + col][g * 8];
            const bf16x8 ap1 = *(const bf16x8*)&P[w][qh * 16 + col][32 + g * 8];
            O[qh][0] = __builtin_amdgcn_mfma_f32_16x16x32_bf16(ap0, bv0, O[qh][0], 0, 0, 0);
            O[qh][0] = __builtin_amdgcn_mfma_f32_16x16x32_bf16(ap1, bv1, O[qh][0], 0, 0, 0);
            O[qh][1] = __builtin_amdgcn_mfma_f32_16x16x32_bf16(ap0, bv2, O[qh][1], 0, 0, 0);
            O[qh][1] = __builtin_amdgcn_mfma_f32_16x16x32_bf16(ap1, bv3, O[qh][1], 0, 0, 0);
            Lacc[qh] = __builtin_amdgcn_mfma_f32_16x16x32_bf16(ap0, ones, Lacc[qh], 0, 0, 0);
            Lacc[qh] = __builtin_amdgcn_mfma_f32_16x16x32_bf16(ap1, ones, Lacc[qh], 0, 0, 0);
        }
    }

    // store partials transposed: pO[t][s][q][d] (reducer reads coalesced)
    const int t = bh * 98 + qt;
    __bf16* po = pO + ((size_t)t * NSPLIT + sp) * 1024;
    #pragma unroll
    for (int qh = 0; qh < 2; ++qh)
        #pragma unroll
        for (int dh = 0; dh < 2; ++dh)
            #pragma unroll
            for (int r = 0; r < 4; ++r)
                po[(qh * 16 + g * 4 + r) * 32 + dh * 16 + col] = (__bf16)O[qh][dh][r];
    if (col == 0) {
        float* plp = pl + ((size_t)t * NSPLIT + sp) * 32;
        *(f32x4*)(plp + g * 4)      = Lacc[0];
        *(f32x4*)(plp + 16 + g * 4) = Lacc[1];
    }
}

// ---------------------------------------------------------------------------
// K3: fused reduce + LePE + proj. grid (98, 2) = 196 blocks, block 256.
// Phase 1: sum 8 split partials, normalize, add LePE(5x5 on vT)+bias ->
// LDS tile at[32 px][128 c]. Phase 2: proj MFMA from LDS, fp32 out.
// ---------------------------------------------------------------------------
__global__ __launch_bounds__(256) void k_rproj(
    const __bf16* __restrict__ pO, const float* __restrict__ pl,
    const __bf16* __restrict__ vT,
    const float* __restrict__ lepe_w, const float* __restrict__ lepe_b,
    const float* __restrict__ proj_w, const float* __restrict__ proj_b,
    float* __restrict__ out)
{
    __shared__ __bf16 at[32][136];         // reduced attn+lepe tile [px][c]
    __shared__ float  wl[CCH][25];
    __shared__ float  bl[CCH];
    const int tid = threadIdx.x;
    const int qt = blockIdx.x, b = blockIdx.y;

    for (int i = tid; i < CCH * 25; i += 256) ((float*)wl)[i] = lepe_w[i];
    if (tid < CCH) bl[tid] = lepe_b[tid];
    __syncthreads();   // wl/bl ready before phase-1 use

    // ---- phase 1: thread = (q, 4-channel group), loop over 4 heads ----
    const int q   = tid >> 3;              // 0..31
    const int cq4 = (tid & 7) * 4;         // 0,4,...,28 within head
    const int px  = qt * 32 + q;
    const int py  = px / WIMG, pxx = px % WIMG;

    #pragma unroll
    for (int h = 0; h < NH; ++h) {
        const int c = h * HD + cq4;
        const size_t t = (size_t)(b * NH + h) * 98 + qt;
        float lt = 0.f;
        float o[4] = {0.f, 0.f, 0.f, 0.f};
        #pragma unroll
        for (int s = 0; s < NSPLIT; ++s) {
            lt += pl[(t * NSPLIT + s) * 32 + q];
            const bf16x4 pv = *(const bf16x4*)(pO + (t * NSPLIT + s) * 1024 + q * 32 + cq4);
            #pragma unroll
            for (int i = 0; i < 4; ++i) o[i] += (float)pv[i];
        }
        const float linv = 1.0f / lt;
        #pragma unroll
        for (int i = 0; i < 4; ++i) o[i] = o[i] * linv + bl[c + i];

        const __bf16* vtb = vT + ((size_t)b * NPIX) * CCH + c;
        #pragma unroll
        for (int dy = 0; dy < 5; ++dy) {
            const int yy = py + dy - 2;
            if (yy < 0 || yy >= WIMG) continue;
            #pragma unroll
            for (int dx = 0; dx < 5; ++dx) {
                const int xx = pxx + dx - 2;
                if (xx < 0 || xx >= WIMG) continue;
                const bf16x4 vv = *(const bf16x4*)(vtb + (size_t)(yy * WIMG + xx) * CCH);
                const int tap = dy * 5 + dx;
                #pragma unroll
                for (int i = 0; i < 4; ++i) o[i] += (float)vv[i] * wl[c + i][tap];
            }
        }
        bf16x4 ov = {(__bf16)o[0], (__bf16)o[1], (__bf16)o[2], (__bf16)o[3]};
        *(bf16x4*)&at[q][c] = ov;
    }
    __syncthreads();

    // ---- phase 2: proj MFMA. wave w -> outputs [w*32, w*32+32), px 0..31 ----
    const int w = tid >> 6, lane = tid & 63;
    const int col = lane & 15, g = lane >> 4;
    const int obase = w * 32;

    #pragma unroll
    for (int ot = 0; ot < 2; ++ot) {
        const float* wrow = proj_w + (size_t)(obase + ot * 16 + col) * CCH;
        f32x4 acc[2];
        acc[0] = (f32x4){0.f, 0.f, 0.f, 0.f};
        acc[1] = (f32x4){0.f, 0.f, 0.f, 0.f};
        #pragma unroll
        for (int ks = 0; ks < 4; ++ks) {
            const int c0 = ks * 32 + g * 8;
            const float4 wA = *(const float4*)(wrow + c0);
            const float4 wB = *(const float4*)(wrow + c0 + 4);
            bf16x8 af = {(__bf16)wA.x, (__bf16)wA.y, (__bf16)wA.z, (__bf16)wA.w,
                         (__bf16)wB.x, (__bf16)wB.y, (__bf16)wB.z, (__bf16)wB.w};
            #pragma unroll
            for (int a = 0; a < 2; ++a) {
                const bf16x8 bf_ = *(const bf16x8*)&at[16 * a + col][c0];
                acc[a] = __builtin_amdgcn_mfma_f32_16x16x32_bf16(af, bf_, acc[a], 0, 0, 0);
            }
        }
        const f32x4 pb = *(const f32x4*)(proj_b + obase + ot * 16 + g * 4);
        #pragma unroll
        for (int a = 0; a < 2; ++a)
            #pragma unroll
            for (int r = 0; r < 4; ++r)
                out[(size_t)(b * CCH + obase + ot * 16 + g * 4 + r) * NPIX
                    + qt * 32 + 16 * a + col] = acc[a][r] + pb[r];
    }
}

// ---------------------------------------------------------------------------
extern "C" void kernel_launch(void* const* d_in, const int* in_sizes, int n_in,
                              void* d_out, int out_size, void* d_ws, size_t ws_size,
                              hipStream_t stream)
{
    const float* x      = (const float*)d_in[0];
    const float* qkv_w  = (const float*)d_in[1];
    const float* qkv_b  = (const float*)d_in[2];
    const float* lepe_w = (const float*)d_in[3];
    const float* lepe_b = (const float*)d_in[4];
    const float* proj_w = (const float*)d_in[5];
    const float* proj_b = (const float*)d_in[6];
    float* out = (float*)d_out;

    char* p = (char*)d_ws;                                   // ~20 MB total
    __bf16* qT = (__bf16*)p;  p += (size_t)2 * NH * NPIX * HD * 2;   // 1.6 MB
    __bf16* kT = (__bf16*)p;  p += (size_t)2 * NH * NPIX * HD * 2;   // 1.6 MB
    __bf16* vT = (__bf16*)p;  p += (size_t)2 * NPIX * CCH * 2;       // 1.6 MB
    __bf16* vP = (__bf16*)p;  p += (size_t)2 * CCH * NPIX * 2;       // 1.6 MB
    __bf16* pO = (__bf16*)p;  p += (size_t)784 * NSPLIT * 1024 * 2;  // 12.8 MB
    float*  pl = (float*)p;                                          // 0.8 MB

    k_qkv  <<<dim3(49, 3, 2),      dim3(256), 0, stream>>>(x, qkv_w, qkv_b, qT, kT, vT, vP);
    k_attn <<<dim3(49, 8, NSPLIT), dim3(128), 0, stream>>>(qT, kT, vP, pO, pl);
    k_rproj<<<dim3(98, 2),         dim3(256), 0, stream>>>(pO, pl, vT, lepe_w, lepe_b,
                                                           proj_w, proj_b, out);
}